// Round 7
// baseline (480.130 us; speedup 1.0000x reference)
//
#include <hip/hip_runtime.h>
#include <hip/hip_fp16.h>

#define NN 100000
#define NE 3200000
#define F 64
#define NR 8
#define NTI 3125               // node tiles = NN/32 (exact: 3125*32 = 100000)
#define SLCAP 1280             // per-tile edge list capacity (mean 1024, +8 sigma)

typedef _Float16 half8 __attribute__((ext_vector_type(8)));
typedef float f32x4 __attribute__((ext_vector_type(4)));
union U4H8 { uint4 u; half8 h; };

// ---------------- zero: tile histogram ---------------------------------------
__global__ __launch_bounds__(256) void zeroh_kernel(int* __restrict__ hist) {
    int i = blockIdx.x * 256 + threadIdx.x;
    if (i < NTI) hist[i] = 0;
}

// ---------------- cvt: x fp32 -> fp16 copy ----------------------------------
__global__ __launch_bounds__(256) void cvt_kernel(
    const float* __restrict__ x, __half* __restrict__ xh)
{
    size_t base = ((size_t)blockIdx.x * 256 + threadIdx.x) * 8;
    float4 a = *(const float4*)(x + base);
    float4 b = *(const float4*)(x + base + 4);
    __half2 h0 = __floats2half2_rn(a.x, a.y);
    __half2 h1 = __floats2half2_rn(a.z, a.w);
    __half2 h2 = __floats2half2_rn(b.x, b.y);
    __half2 h3 = __floats2half2_rn(b.z, b.w);
    uint4 o;
    o.x = *(unsigned*)&h0; o.y = *(unsigned*)&h1;
    o.z = *(unsigned*)&h2; o.w = *(unsigned*)&h3;
    *(uint4*)(xh + base) = o;
}

// ---------------- cvtw: {root, weight} -> fp16 TRANSPOSED wt9[s][n][k] ------
__global__ __launch_bounds__(256) void cvtw_kernel(
    const float* __restrict__ weight, const float* __restrict__ root,
    __half* __restrict__ wt9)
{
    int gid = blockIdx.x * 256 + threadIdx.x;   // 0..36863
    int s = gid >> 12;
    int rem = gid & 4095;
    int k = rem >> 6, n = rem & 63;
    const float* src = (s == 0) ? root : (weight + ((size_t)(s - 1) << 12));
    wt9[((size_t)s << 12) + (n << 6) + k] = __float2half_rn(src[(k << 6) + n]);
}

// ---------------- count: per-tile edge histogram ----------------------------
// 391 blocks x 8192 edges. LDS hist -> one global atomicAdd per touched tile.
__global__ __launch_bounds__(256) void count_kernel(
    const int* __restrict__ edst, int* __restrict__ hist)
{
    __shared__ int h[NTI];
    const int t = threadIdx.x;
    for (int i = t; i < NTI; i += 256) h[i] = 0;
    __syncthreads();
    const int e0 = blockIdx.x * 8192;
#pragma unroll
    for (int j = 0; j < 32; j++) {
        int e = e0 + (j << 8) + t;
        if (e < NE) atomicAdd(&h[((unsigned)edst[e]) >> 5], 1);
    }
    __syncthreads();
    for (int i = t; i < NTI; i += 256) {
        int v = h[i];
        if (v) atomicAdd(&hist[i], v);
    }
}

// ---------------- scan: exclusive prefix over 3125 counts -------------------
// One block, 13 values/thread, wave shfl scan. Writes tilestart[3126] and a
// working copy cursor[3125] for the scatter pass.
__global__ __launch_bounds__(256) void scan_kernel(
    const int* __restrict__ hist, int* __restrict__ tilestart,
    int* __restrict__ cursor)
{
    __shared__ int wsum[4];
    const int t = threadIdx.x;
    const int lane = t & 63;
    const int wid = t >> 6;
    const int c0 = t * 13;
    int loc[13];
    int s = 0;
#pragma unroll
    for (int j = 0; j < 13; j++) {
        int c = c0 + j;
        int v = (c < NTI) ? hist[c] : 0;
        loc[j] = s;
        s += v;
    }
    int v = s;
#pragma unroll
    for (int off = 1; off < 64; off <<= 1) {
        int u = __shfl_up(v, off);
        if (lane >= off) v += u;
    }
    if (lane == 63) wsum[wid] = v;
    __syncthreads();
    int wo = 0;
#pragma unroll
    for (int w = 0; w < 3; w++) if (w < wid) wo += wsum[w];
    const int base = wo + v - s;           // exclusive prefix for this thread
#pragma unroll
    for (int j = 0; j < 13; j++) {
        int c = c0 + j;
        if (c < NTI) {
            int b = base + loc[j];
            tilestart[c] = b;
            cursor[c] = b;
        }
    }
    if (t == 255) tilestart[NTI] = wo + v;  // = NE
}

// ---------------- scatter: edges -> final per-tile slots --------------------
// 3125 blocks x 1024 edges (exact). Per edge: pack u32, global atomicAdd on
// the tile cursor, direct store. Scattered 4B stores land in a 12.8 MB
// surface that fits aggregate L2 (~1.6 MB/XCD slice) -> HBM writeback is the
// 12.8 MB payload only; no LDS sort needed.
__global__ __launch_bounds__(256) void scatter_kernel(
    const int* __restrict__ esrc, const int* __restrict__ edst,
    const int* __restrict__ etyp,
    int* __restrict__ cursor, unsigned* __restrict__ packed4)
{
    const int e0 = blockIdx.x * 1024 + threadIdx.x;
#pragma unroll
    for (int j = 0; j < 4; j++) {
        int e = e0 + (j << 8);
        unsigned s = (unsigned)esrc[e];
        unsigned d = (unsigned)edst[e];
        unsigned r = (unsigned)etyp[e];
        int tile = (int)(d >> 5);
        int slot = atomicAdd(&cursor[tile], 1);
        // key8 = rel*32 + (d&31) in bits [17..24] -> fused key = p>>17
        packed4[slot] = s | ((d & 31u) << 17) | (r << 22);
    }
}

// ---------------- fused: sort + fp16 gather + MFMA GEMM ---------------------
// Round-7 change: binA/binB (2-level LDS multisplit, ~125us, 9 edge-touches)
// replaced by count+scan+scatter counting sort (5 edge-touches); fused now
// reads ONE contiguous per-tile run [tilestart[t], tilestart[t+1]) and does
// its 256-key sort as before. GEMM is v_mfma_f32_16x16x32_f16 (round 6).
__global__ __launch_bounds__(128, 4) void fused_kernel(
    const __half* __restrict__ xh,
    const unsigned* __restrict__ packed4,
    const int* __restrict__ tilestart,
    const __half* __restrict__ wt9,     // [9][64 fout][64 k] fp16 (0 = root)
    const float* __restrict__ bias,
    float* __restrict__ out)
{
    __shared__ __align__(16) char Asb[32 * 128];   // As[node][k] fp16, swizzled, 4 KB
    __shared__ __align__(16) char Wtb[64 * 128];   // Wt[fout][k] fp16, swizzled, 8 KB
    __shared__ int kstart[257];                    // run starts; [256] = total
    __shared__ int slist[SLCAP];                   // 5 KB
    __shared__ int wsum[2];
    int* const kcur = (int*)Asb;         // overlay: dead until staging begins

    const int t = threadIdx.x;
    const int tile = blockIdx.x;
    const int lane = t & 63;
    const int wid = t >> 6;

    const int ebase0 = tilestart[tile];
    const int rc = min(tilestart[tile + 1] - ebase0, SLCAP);

    kstart[t] = 0; kstart[t + 128] = 0;
    __syncthreads();

    // ---- hist by key8 = rel*32 + dstLow5; register-cache the run ----
    unsigned pc[10];
#pragma unroll
    for (int j = 0; j < 10; j++) {
        int i = t + (j << 7);
        if (i < rc) {
            pc[j] = packed4[ebase0 + i];
            atomicAdd(&kstart[pc[j] >> 17], 1);
        }
    }
    __syncthreads();

    // ---- exclusive scan of 256 counts: 2 keys/thread, wave shfl scan ----
    const int a0 = kstart[2 * t], a1 = kstart[2 * t + 1];
    int v = a0 + a1;
#pragma unroll
    for (int off = 1; off < 64; off <<= 1) {
        int u = __shfl_up(v, off);
        if (lane >= off) v += u;
    }
    if (lane == 63) wsum[wid] = v;
    __syncthreads();                       // orders kstart reads vs writes below
    const int wo = wid ? wsum[0] : 0;
    const int incl = wo + v;
    const int ebase = incl - a0 - a1;
    kstart[2 * t]     = ebase;
    kstart[2 * t + 1] = ebase + a0;
    kcur[2 * t]       = ebase;
    kcur[2 * t + 1]   = ebase + a0;
    if (t == 127) kstart[256] = incl;      // total edge count
    __syncthreads();

    // ---- scatter into per-key runs (LDS slist; packed4 from registers) ----
#pragma unroll
    for (int j = 0; j < 10; j++) {
        int i = t + (j << 7);
        if (i < rc) {
            int slot = atomicAdd(&kcur[pc[j] >> 17], 1);
            slist[slot] = (int)(pc[j] & 0x1FFFFu);
        }
    }
    __syncthreads();   // sort frozen; kcur (Asb) dead

    // ---- per-seg: stage Wt -> gather As (wave-private fp16) -> MFMA --------
    const int node0 = tile * 32;
    const int w16 = wid << 4;             // wave's 16-node slice
    const int sn  = w16 + (lane >> 2);    // gather: node within tile 0..31
    const int sq  = lane & 3;             // gather: k-eighth 0..3
    const int kb  = sq << 3;              // halfs [kb,kb+8) and [32+kb,...)
    const unsigned snswz = (unsigned)((sn & 7) << 4);
    char* const awp = Asb + sn * 128;

    // MFMA fragment indices
    const int ml = lane & 15;             // 16-dim: node (A) / fout (B,D)
    const int kg = lane >> 4;             // k-group 0..3
    const int arow = w16 + ml;            // A row = node within tile
    const unsigned aswz = (unsigned)((arow & 7) << 4);
    const unsigned kb0 = (unsigned)(kg << 4);   // kbyte within 64B k-half

    f32x4 acc[4];
#pragma unroll
    for (int nt = 0; nt < 4; nt++)
#pragma unroll
        for (int i = 0; i < 4; i++) acc[nt][i] = 0.f;

    for (int seg = 0; seg < 9; seg++) {
        if (seg) __syncthreads();          // all waves done reading Wtb(seg-1)

        // stage Wt(seg) -> LDS with XOR swizzle (coalesced fp16 source)
        {
            const uint4* __restrict__ wsrc = (const uint4*)(wt9 + ((size_t)seg << 12));
#pragma unroll
            for (int j = 0; j < 4; j++) {
                int c = t + (j << 7);                       // 0..511
                int n = c >> 3;
                unsigned kbyt = (unsigned)((c & 7) << 4);
                *(uint4*)(Wtb + n * 128 + (kbyt ^ (unsigned)((n & 7) << 4))) = wsrc[c];
            }
        }

        if (seg == 0) {
            // root: copy own-row xh straight into As (fp16, swizzled)
            const __half* rowp = xh + (size_t)(node0 + sn) * F + kb;
            uint4 va = *(const uint4*)(rowp);
            uint4 vb = *(const uint4*)(rowp + 32);
            *(uint4*)(awp + (((unsigned)(sq << 4)) ^ snswz)) = va;
            *(uint4*)(awp + ((64u | (unsigned)(sq << 4)) ^ snswz)) = vb;
        } else {
            // mean-gather this wave's 16 nodes for relation seg-1 (fp16 rows)
            const int key = ((seg - 1) << 5) | sn;
            const int beg = kstart[key];
            const int end = kstart[key + 1];   // prefix property: next start
            float4 A0 = make_float4(0.f, 0.f, 0.f, 0.f);
            float4 A1 = A0, B0 = A0, B1 = A0;
            int i = beg;
            for (; i + 4 <= end; i += 4) {     // 4-edge unroll
                const __half* h0 = xh + (size_t)slist[i]     * F + kb;
                const __half* h1 = xh + (size_t)slist[i + 1] * F + kb;
                const __half* h2 = xh + (size_t)slist[i + 2] * F + kb;
                const __half* h3 = xh + (size_t)slist[i + 3] * F + kb;
                uint4 la0 = *(const uint4*)(h0);      uint4 lb0 = *(const uint4*)(h0 + 32);
                uint4 la1 = *(const uint4*)(h1);      uint4 lb1 = *(const uint4*)(h1 + 32);
                uint4 la2 = *(const uint4*)(h2);      uint4 lb2 = *(const uint4*)(h2 + 32);
                uint4 la3 = *(const uint4*)(h3);      uint4 lb3 = *(const uint4*)(h3 + 32);
#define ACC8(v, P, Q) { \
                float2 t0 = __half22float2(*(const __half2*)&(v).x); \
                float2 t1 = __half22float2(*(const __half2*)&(v).y); \
                float2 t2 = __half22float2(*(const __half2*)&(v).z); \
                float2 t3 = __half22float2(*(const __half2*)&(v).w); \
                P.x += t0.x; P.y += t0.y; P.z += t1.x; P.w += t1.y; \
                Q.x += t2.x; Q.y += t2.y; Q.z += t3.x; Q.w += t3.y; }
                ACC8(la0, A0, A1) ACC8(la1, A0, A1) ACC8(la2, A0, A1) ACC8(la3, A0, A1)
                ACC8(lb0, B0, B1) ACC8(lb1, B0, B1) ACC8(lb2, B0, B1) ACC8(lb3, B0, B1)
            }
            for (; i < end; i++) {
                const __half* h0 = xh + (size_t)slist[i] * F + kb;
                uint4 la = *(const uint4*)(h0);
                uint4 lb = *(const uint4*)(h0 + 32);
                ACC8(la, A0, A1)
                ACC8(lb, B0, B1)
            }
#undef ACC8
            const float scl = 1.0f / (float)max(end - beg, 1);
            __half2 p0 = __floats2half2_rn(A0.x * scl, A0.y * scl);
            __half2 p1 = __floats2half2_rn(A0.z * scl, A0.w * scl);
            __half2 p2 = __floats2half2_rn(A1.x * scl, A1.y * scl);
            __half2 p3 = __floats2half2_rn(A1.z * scl, A1.w * scl);
            __half2 q0 = __floats2half2_rn(B0.x * scl, B0.y * scl);
            __half2 q1 = __floats2half2_rn(B0.z * scl, B0.w * scl);
            __half2 q2 = __floats2half2_rn(B1.x * scl, B1.y * scl);
            __half2 q3 = __floats2half2_rn(B1.z * scl, B1.w * scl);
            uint4 pa, pb;
            pa.x = *(unsigned*)&p0; pa.y = *(unsigned*)&p1;
            pa.z = *(unsigned*)&p2; pa.w = *(unsigned*)&p3;
            pb.x = *(unsigned*)&q0; pb.y = *(unsigned*)&q1;
            pb.z = *(unsigned*)&q2; pb.w = *(unsigned*)&q3;
            *(uint4*)(awp + (((unsigned)(sq << 4)) ^ snswz)) = pa;
            *(uint4*)(awp + ((64u | (unsigned)(sq << 4)) ^ snswz)) = pb;
        }
        __syncthreads();                   // Wtb(seg) staged & visible

        // MFMA GEMM: D[16 node x 64 fout] += A[16x64] * W[64x64]
        U4H8 fa0, fa1;
        fa0.u = *(const uint4*)(Asb + arow * 128 + (kb0 ^ aswz));
        fa1.u = *(const uint4*)(Asb + arow * 128 + ((64u | kb0) ^ aswz));
#pragma unroll
        for (int nt = 0; nt < 4; nt++) {
            int wrow = (nt << 4) + ml;
            unsigned wswz = (unsigned)((wrow & 7) << 4);
            U4H8 fb0, fb1;
            fb0.u = *(const uint4*)(Wtb + wrow * 128 + (kb0 ^ wswz));
            fb1.u = *(const uint4*)(Wtb + wrow * 128 + ((64u | kb0) ^ wswz));
            acc[nt] = __builtin_amdgcn_mfma_f32_16x16x32_f16(fa0.h, fb0.h, acc[nt], 0, 0, 0);
            acc[nt] = __builtin_amdgcn_mfma_f32_16x16x32_f16(fa1.h, fb1.h, acc[nt], 0, 0, 0);
        }
    }

    // epilogue: + bias; D mapping col=lane&15, row=(lane>>4)*4+i (verified)
#pragma unroll
    for (int nt = 0; nt < 4; nt++) {
        float bb = bias[(nt << 4) + ml];
#pragma unroll
        for (int i = 0; i < 4; i++) {
            int node = node0 + w16 + (kg << 2) + i;
            out[(size_t)node * F + (nt << 4) + ml] = acc[nt][i] + bb;
        }
    }
}

extern "C" void kernel_launch(void* const* d_in, const int* in_sizes, int n_in,
                              void* d_out, int out_size, void* d_ws, size_t ws_size,
                              hipStream_t stream) {
    const float* x    = (const float*)d_in[0];
    const int*   ei   = (const int*)d_in[1];
    const int*   et   = (const int*)d_in[2];
    const float* wgt  = (const float*)d_in[3];
    const float* root = (const float*)d_in[4];
    const float* bias = (const float*)d_in[5];
    float*       out  = (float*)d_out;

    char* ws = (char*)d_ws;
    int*      hist      = (int*)ws;                        // [3125]   (12.5 KB)
    int*      tilestart = (int*)(ws + 16384);              // [3126]   (12.5 KB)
    int*      cursor    = (int*)(ws + 32768);              // [3125]   (12.5 KB)
    unsigned* packed4   = (unsigned*)(ws + 49152);         // [NE]     (12.8 MB)
    __half*   xh        = (__half*)(ws + 49152 + (size_t)NE * 4);   // 12.8 MB
    __half*   wt9       = xh + (size_t)NN * F;                      // 72 KB

    zeroh_kernel<<<13, 256, 0, stream>>>(hist);
    cvt_kernel<<<NN * F / (256 * 8), 256, 0, stream>>>(x, xh);
    cvtw_kernel<<<144, 256, 0, stream>>>(wgt, root, wt9);
    count_kernel<<<(NE + 8191) / 8192, 256, 0, stream>>>(ei + NE, hist);
    scan_kernel<<<1, 256, 0, stream>>>(hist, tilestart, cursor);
    scatter_kernel<<<NE / 1024, 256, 0, stream>>>(ei, ei + NE, et, cursor, packed4);
    fused_kernel<<<NTI, 128, 0, stream>>>(xh, packed4, tilestart, wt9, bias, out);
}

// Round 8
// 227.633 us; speedup vs baseline: 2.1092x; 2.1092x over previous
//
#include <hip/hip_runtime.h>
#include <hip/hip_fp16.h>

#define NN 100000
#define NE 3200000
#define F 64
#define NR 8
#define NCB 98                 // coarse buckets = ceil(NN/1024), bucket = dst>>10
#define CAPC 36864             // capacity per coarse bucket
#define CHUNKA 4000            // edges per binA block (800 blocks)
#define NT 3125                // node tiles = NN/32 (exact: 3125*32 = 100000)
#define SLCAP 1280             // per-tile edge list capacity (mean 1024, +8 sigma)

typedef _Float16 half8 __attribute__((ext_vector_type(8)));
typedef float f32x4 __attribute__((ext_vector_type(4)));
union U4H8 { uint4 u; half8 h; };

// ---------------- init: per-coarse-bucket staging cursors -------------------
__global__ __launch_bounds__(128) void init_kernel(int* __restrict__ cursors) {
    int t = threadIdx.x;
    if (t < NCB) cursors[t] = t * CAPC;
}

// ---------------- cvt: x fp32 -> fp16 copy ----------------------------------
__global__ __launch_bounds__(256) void cvt_kernel(
    const float* __restrict__ x, __half* __restrict__ xh)
{
    size_t base = ((size_t)blockIdx.x * 256 + threadIdx.x) * 8;
    float4 a = *(const float4*)(x + base);
    float4 b = *(const float4*)(x + base + 4);
    __half2 h0 = __floats2half2_rn(a.x, a.y);
    __half2 h1 = __floats2half2_rn(a.z, a.w);
    __half2 h2 = __floats2half2_rn(b.x, b.y);
    __half2 h3 = __floats2half2_rn(b.z, b.w);
    uint4 o;
    o.x = *(unsigned*)&h0; o.y = *(unsigned*)&h1;
    o.z = *(unsigned*)&h2; o.w = *(unsigned*)&h3;
    *(uint4*)(xh + base) = o;
}

// ---------------- cvtw: {root, weight} -> fp16 TRANSPOSED wt9[s][n][k] ------
__global__ __launch_bounds__(256) void cvtw_kernel(
    const float* __restrict__ weight, const float* __restrict__ root,
    __half* __restrict__ wt9)
{
    int gid = blockIdx.x * 256 + threadIdx.x;   // 0..36863
    int s = gid >> 12;
    int rem = gid & 4095;
    int k = rem >> 6, n = rem & 63;
    const float* src = (s == 0) ? root : (weight + ((size_t)(s - 1) << 12));
    wt9[((size_t)s << 12) + (n << 6) + k] = __float2half_rn(src[(k << 6) + n]);
}

// ---------------- pass A: coarse-bin edges (4-copy LDS multi-split) ---------
// Round-8 tune: u32 payload packed AT LOAD (recs 32->16 KB LDS + 4 KB bucket
// bytes); uint4 vectorized edge loads (4 edges per load instr per array).
__global__ __launch_bounds__(256) void binA_kernel(
    const int* __restrict__ esrc, const int* __restrict__ edst,
    const int* __restrict__ etyp,
    int* __restrict__ cursors, unsigned* __restrict__ stag4)
{
    __shared__ int hist[128][4];
    __shared__ int start[128];
    __shared__ int cur[128][4];
    __shared__ int gbase[NCB];
    __shared__ unsigned recs[CHUNKA];        // 16 KB packed payloads
    __shared__ unsigned char bks[CHUNKA];    // 4 KB bucket ids

    const int t = threadIdx.x;
    const int cp = t & 3;
    const int e0 = blockIdx.x * CHUNKA;

    if (t < 128) ((int4*)hist)[t] = make_int4(0, 0, 0, 0);
    __syncthreads();

    // load 4 groups of 4 edges (uint4); 1000 groups total
    unsigned pay[4][4];
    unsigned bk4[4];
    const uint4* sv4 = (const uint4*)(esrc + e0);
    const uint4* dv4 = (const uint4*)(edst + e0);
    const uint4* rv4 = (const uint4*)(etyp + e0);
#pragma unroll
    for (int j = 0; j < 4; j++) {
        int g = t + (j << 8);
        if (g < CHUNKA / 4) {
            uint4 sv = sv4[g];
            uint4 dv = dv4[g];
            uint4 rv = rv4[g];
            unsigned b0 = dv.x >> 10, b1 = dv.y >> 10, b2 = dv.z >> 10, b3 = dv.w >> 10;
            pay[j][0] = sv.x | ((dv.x & 1023u) << 17) | (rv.x << 27);
            pay[j][1] = sv.y | ((dv.y & 1023u) << 17) | (rv.y << 27);
            pay[j][2] = sv.z | ((dv.z & 1023u) << 17) | (rv.z << 27);
            pay[j][3] = sv.w | ((dv.w & 1023u) << 17) | (rv.w << 27);
            bk4[j] = b0 | (b1 << 8) | (b2 << 16) | (b3 << 24);
            atomicAdd(&hist[b0][cp], 1);
            atomicAdd(&hist[b1][cp], 1);
            atomicAdd(&hist[b2][cp], 1);
            atomicAdd(&hist[b3][cp], 1);
        }
    }
    __syncthreads();

    int tot = 0;
    if (t < 128) {
        int4 h4 = ((int4*)hist)[t];
        tot = h4.x + h4.y + h4.z + h4.w;
        start[t] = tot;
    }
    __syncthreads();
    for (int off = 1; off < 128; off <<= 1) {
        int v = 0;
        if (t < 128 && t >= off) v = start[t - off];
        __syncthreads();
        if (t < 128) start[t] += v;
        __syncthreads();
    }
    if (t < 128) start[t] -= tot;   // inclusive -> exclusive
    __syncthreads();
    if (t < NCB) {
        int4 h4 = ((int4*)hist)[t];
        int s = start[t];
        cur[t][0] = s;
        cur[t][1] = s + h4.x;
        cur[t][2] = s + h4.x + h4.y;
        cur[t][3] = s + h4.x + h4.y + h4.z;
        gbase[t] = atomicAdd(&cursors[t], tot);
    }
    __syncthreads();

#pragma unroll
    for (int j = 0; j < 4; j++) {
        int g = t + (j << 8);
        if (g < CHUNKA / 4) {
#pragma unroll
            for (int k = 0; k < 4; k++) {
                int b = (int)((bk4[j] >> (k << 3)) & 255u);
                int slot = atomicAdd(&cur[b][cp], 1);
                recs[slot] = pay[j][k];
                bks[slot] = (unsigned char)b;
            }
        }
    }
    __syncthreads();

#pragma unroll
    for (int j = 0; j < 16; j++) {
        int i = t + (j << 8);
        if (i < CHUNKA) {
            int b = (int)bks[i];
            stag4[gbase[b] + (i - start[b])] = recs[i];
        }
    }
}

// ---------------- pass B: fine-bin to 32-node buckets, 8 chunks/coarse ------
// Round-8 tune: chunk register-cached on first read (no second global pass);
// uint4 loads (4-aligned chunk boundaries); 32-lane shfl scan replaces the
// t==0 serial 128-op scan.
__global__ __launch_bounds__(256) void binB_kernel(
    const unsigned* __restrict__ stag4, const int* __restrict__ cursors,
    unsigned* __restrict__ packed4, unsigned* __restrict__ runsd)
{
    __shared__ int h[32][4];
    __shared__ int cu[32][4];
    const int b = blockIdx.x >> 3;
    const int c = blockIdx.x & 7;
    const int t = threadIdx.x;
    const int cp = t & 3;
    const int bbase = b * CAPC;
    const int n = cursors[b] - bbase;
    const int s = (c == 0) ? 0 : (int)((((long long)c * n) >> 3) & ~3LL);
    const int e = (c == 7) ? n : (int)((((long long)(c + 1) * n) >> 3) & ~3LL);
    const int base = bbase + s;
    const int cn = e - s;

    if (t < 128) ((int*)h)[t] = 0;
    __syncthreads();

    // load + hist: 5 groups of 4 (cn <= ~4300), reg-cached
    unsigned pc[5][4];
    const uint4* src4 = (const uint4*)(stag4 + base);
#pragma unroll
    for (int j = 0; j < 5; j++) {
        int idx = (t + (j << 8)) << 2;
        if (idx < cn) {
            uint4 v = src4[t + (j << 8)];
            pc[j][0] = v.x; pc[j][1] = v.y; pc[j][2] = v.z; pc[j][3] = v.w;
#pragma unroll
            for (int k = 0; k < 4; k++)
                if (idx + k < cn) atomicAdd(&h[(pc[j][k] >> 22) & 31][cp], 1);
        }
    }
    __syncthreads();

    // 32-lane shfl scan over per-tile totals
    if (t < 32) {
        int h0 = h[t][0], h1 = h[t][1], h2 = h[t][2], h3 = h[t][3];
        int tot = h0 + h1 + h2 + h3;
        int v = tot;
#pragma unroll
        for (int off = 1; off < 32; off <<= 1) {
            int u = __shfl_up(v, off);
            if (t >= off) v += u;
        }
        int eb = v - tot;                  // exclusive within chunk
        cu[t][0] = eb;
        cu[t][1] = eb + h0;
        cu[t][2] = eb + h0 + h1;
        cu[t][3] = eb + h0 + h1 + h2;
        runsd[(blockIdx.x << 5) + t] = ((unsigned)(base + eb) << 10) | (unsigned)tot;
    }
    __syncthreads();

    // scatter from registers
#pragma unroll
    for (int j = 0; j < 5; j++) {
        int idx = (t + (j << 8)) << 2;
        if (idx < cn) {
#pragma unroll
            for (int k = 0; k < 4; k++) {
                if (idx + k < cn) {
                    unsigned v = pc[j][k];
                    unsigned f = (v >> 22) & 31u;
                    int p = atomicAdd(&cu[f][cp], 1);
                    unsigned d5  = (v >> 17) & 31u;
                    unsigned rel = v >> 27;
                    // key8 = rel*32 + d5 in bits [17..24] -> fused key = p>>17
                    packed4[base + p] = (v & 0x1FFFFu) | (d5 << 17) | (rel << 22);
                }
            }
        }
    }
}

// ---------------- fused: sort + fp16 gather + MFMA GEMM (round-6, proven) ---
__global__ __launch_bounds__(128, 4) void fused_kernel(
    const __half* __restrict__ xh,
    const unsigned* __restrict__ packed4,
    const unsigned* __restrict__ runsd,
    const __half* __restrict__ wt9,     // [9][64 fout][64 k] fp16 (0 = root)
    const float* __restrict__ bias,
    float* __restrict__ out)
{
    __shared__ __align__(16) char Asb[32 * 128];   // As[node][k] fp16, swizzled, 4 KB
    __shared__ __align__(16) char Wtb[64 * 128];   // Wt[fout][k] fp16, swizzled, 8 KB
    __shared__ int kstart[257];                    // run starts; [256] = total
    __shared__ int slist[SLCAP];                   // 5 KB
    __shared__ unsigned rdesc[8];
    __shared__ int wsum[2];
    int* const kcur = (int*)Asb;         // overlay: dead until staging begins

    const int t = threadIdx.x;
    const int tile = blockIdx.x;
    const int lane = t & 63;
    const int wid = t >> 6;

    if (t < 8) rdesc[t] = runsd[(((tile >> 5) * 8 + t) << 5) + (tile & 31)];
    kstart[t] = 0; kstart[t + 128] = 0;
    __syncthreads();

    // ---- hist by key8 = rel*32 + dstLow5; register-cache first iteration ----
    unsigned pc[8];
#pragma unroll
    for (int c = 0; c < 8; c++) {
        unsigned d = rdesc[c];
        int rs = (int)(d >> 10), rc = (int)(d & 1023u);
        if (t < rc) {
            pc[c] = packed4[rs + t];
            atomicAdd(&kstart[pc[c] >> 17], 1);
        }
        for (int i = t + 128; i < rc; i += 128)          // rare (rc > 128)
            atomicAdd(&kstart[packed4[rs + i] >> 17], 1);
    }
    __syncthreads();

    // ---- exclusive scan of 256 counts: 2 keys/thread, wave shfl scan ----
    const int a0 = kstart[2 * t], a1 = kstart[2 * t + 1];
    int v = a0 + a1;
#pragma unroll
    for (int off = 1; off < 64; off <<= 1) {
        int u = __shfl_up(v, off);
        if (lane >= off) v += u;
    }
    if (lane == 63) wsum[wid] = v;
    __syncthreads();                       // orders kstart reads vs writes below
    const int wo = wid ? wsum[0] : 0;
    const int incl = wo + v;
    const int ebase = incl - a0 - a1;
    kstart[2 * t]     = ebase;
    kstart[2 * t + 1] = ebase + a0;
    kcur[2 * t]       = ebase;
    kcur[2 * t + 1]   = ebase + a0;
    if (t == 127) kstart[256] = incl;      // total edge count
    __syncthreads();

    // ---- scatter into per-key runs (LDS slist; packed4 from registers) ----
#pragma unroll
    for (int c = 0; c < 8; c++) {
        unsigned d = rdesc[c];
        int rs = (int)(d >> 10), rc = (int)(d & 1023u);
        if (t < rc) {
            int slot = atomicAdd(&kcur[pc[c] >> 17], 1);
            slist[slot] = (int)(pc[c] & 0x1FFFFu);
        }
        for (int i = t + 128; i < rc; i += 128) {        // rare (rc > 128)
            unsigned p = packed4[rs + i];
            int slot = atomicAdd(&kcur[p >> 17], 1);
            slist[slot] = (int)(p & 0x1FFFFu);
        }
    }
    __syncthreads();   // sort frozen; kcur (Asb) dead

    // ---- per-seg: stage Wt -> gather As (wave-private fp16) -> MFMA --------
    const int node0 = tile * 32;
    const int w16 = wid << 4;             // wave's 16-node slice
    const int sn  = w16 + (lane >> 2);    // gather: node within tile 0..31
    const int sq  = lane & 3;             // gather: k-eighth 0..3
    const int kb  = sq << 3;              // halfs [kb,kb+8) and [32+kb,...)
    const unsigned snswz = (unsigned)((sn & 7) << 4);
    char* const awp = Asb + sn * 128;

    // MFMA fragment indices
    const int ml = lane & 15;             // 16-dim: node (A) / fout (B,D)
    const int kg = lane >> 4;             // k-group 0..3
    const int arow = w16 + ml;            // A row = node within tile
    const unsigned aswz = (unsigned)((arow & 7) << 4);
    const unsigned kb0 = (unsigned)(kg << 4);   // kbyte within 64B k-half

    f32x4 acc[4];
#pragma unroll
    for (int nt = 0; nt < 4; nt++)
#pragma unroll
        for (int i = 0; i < 4; i++) acc[nt][i] = 0.f;

    for (int seg = 0; seg < 9; seg++) {
        if (seg) __syncthreads();          // all waves done reading Wtb(seg-1)

        // stage Wt(seg) -> LDS with XOR swizzle (coalesced fp16 source)
        {
            const uint4* __restrict__ wsrc = (const uint4*)(wt9 + ((size_t)seg << 12));
#pragma unroll
            for (int j = 0; j < 4; j++) {
                int c = t + (j << 7);                       // 0..511
                int n = c >> 3;
                unsigned kbyt = (unsigned)((c & 7) << 4);
                *(uint4*)(Wtb + n * 128 + (kbyt ^ (unsigned)((n & 7) << 4))) = wsrc[c];
            }
        }

        if (seg == 0) {
            // root: copy own-row xh straight into As (fp16, swizzled)
            const __half* rowp = xh + (size_t)(node0 + sn) * F + kb;
            uint4 va = *(const uint4*)(rowp);
            uint4 vb = *(const uint4*)(rowp + 32);
            *(uint4*)(awp + (((unsigned)(sq << 4)) ^ snswz)) = va;
            *(uint4*)(awp + ((64u | (unsigned)(sq << 4)) ^ snswz)) = vb;
        } else {
            // mean-gather this wave's 16 nodes for relation seg-1 (fp16 rows)
            const int key = ((seg - 1) << 5) | sn;
            const int beg = kstart[key];
            const int end = kstart[key + 1];   // prefix property: next start
            float4 A0 = make_float4(0.f, 0.f, 0.f, 0.f);
            float4 A1 = A0, B0 = A0, B1 = A0;
            int i = beg;
            for (; i + 4 <= end; i += 4) {     // 4-edge unroll
                const __half* h0 = xh + (size_t)slist[i]     * F + kb;
                const __half* h1 = xh + (size_t)slist[i + 1] * F + kb;
                const __half* h2 = xh + (size_t)slist[i + 2] * F + kb;
                const __half* h3 = xh + (size_t)slist[i + 3] * F + kb;
                uint4 la0 = *(const uint4*)(h0);      uint4 lb0 = *(const uint4*)(h0 + 32);
                uint4 la1 = *(const uint4*)(h1);      uint4 lb1 = *(const uint4*)(h1 + 32);
                uint4 la2 = *(const uint4*)(h2);      uint4 lb2 = *(const uint4*)(h2 + 32);
                uint4 la3 = *(const uint4*)(h3);      uint4 lb3 = *(const uint4*)(h3 + 32);
#define ACC8(v, P, Q) { \
                float2 t0 = __half22float2(*(const __half2*)&(v).x); \
                float2 t1 = __half22float2(*(const __half2*)&(v).y); \
                float2 t2 = __half22float2(*(const __half2*)&(v).z); \
                float2 t3 = __half22float2(*(const __half2*)&(v).w); \
                P.x += t0.x; P.y += t0.y; P.z += t1.x; P.w += t1.y; \
                Q.x += t2.x; Q.y += t2.y; Q.z += t3.x; Q.w += t3.y; }
                ACC8(la0, A0, A1) ACC8(la1, A0, A1) ACC8(la2, A0, A1) ACC8(la3, A0, A1)
                ACC8(lb0, B0, B1) ACC8(lb1, B0, B1) ACC8(lb2, B0, B1) ACC8(lb3, B0, B1)
            }
            for (; i < end; i++) {
                const __half* h0 = xh + (size_t)slist[i] * F + kb;
                uint4 la = *(const uint4*)(h0);
                uint4 lb = *(const uint4*)(h0 + 32);
                ACC8(la, A0, A1)
                ACC8(lb, B0, B1)
            }
#undef ACC8
            const float scl = 1.0f / (float)max(end - beg, 1);
            __half2 p0 = __floats2half2_rn(A0.x * scl, A0.y * scl);
            __half2 p1 = __floats2half2_rn(A0.z * scl, A0.w * scl);
            __half2 p2 = __floats2half2_rn(A1.x * scl, A1.y * scl);
            __half2 p3 = __floats2half2_rn(A1.z * scl, A1.w * scl);
            __half2 q0 = __floats2half2_rn(B0.x * scl, B0.y * scl);
            __half2 q1 = __floats2half2_rn(B0.z * scl, B0.w * scl);
            __half2 q2 = __floats2half2_rn(B1.x * scl, B1.y * scl);
            __half2 q3 = __floats2half2_rn(B1.z * scl, B1.w * scl);
            uint4 pa, pb;
            pa.x = *(unsigned*)&p0; pa.y = *(unsigned*)&p1;
            pa.z = *(unsigned*)&p2; pa.w = *(unsigned*)&p3;
            pb.x = *(unsigned*)&q0; pb.y = *(unsigned*)&q1;
            pb.z = *(unsigned*)&q2; pb.w = *(unsigned*)&q3;
            *(uint4*)(awp + (((unsigned)(sq << 4)) ^ snswz)) = pa;
            *(uint4*)(awp + ((64u | (unsigned)(sq << 4)) ^ snswz)) = pb;
        }
        __syncthreads();                   // Wtb(seg) staged & visible

        // MFMA GEMM: D[16 node x 64 fout] += A[16x64] * W[64x64]
        U4H8 fa0, fa1;
        fa0.u = *(const uint4*)(Asb + arow * 128 + (kb0 ^ aswz));
        fa1.u = *(const uint4*)(Asb + arow * 128 + ((64u | kb0) ^ aswz));
#pragma unroll
        for (int nt = 0; nt < 4; nt++) {
            int wrow = (nt << 4) + ml;
            unsigned wswz = (unsigned)((wrow & 7) << 4);
            U4H8 fb0, fb1;
            fb0.u = *(const uint4*)(Wtb + wrow * 128 + (kb0 ^ wswz));
            fb1.u = *(const uint4*)(Wtb + wrow * 128 + ((64u | kb0) ^ wswz));
            acc[nt] = __builtin_amdgcn_mfma_f32_16x16x32_f16(fa0.h, fb0.h, acc[nt], 0, 0, 0);
            acc[nt] = __builtin_amdgcn_mfma_f32_16x16x32_f16(fa1.h, fb1.h, acc[nt], 0, 0, 0);
        }
    }

    // epilogue: + bias; D mapping col=lane&15, row=(lane>>4)*4+i (verified)
#pragma unroll
    for (int nt = 0; nt < 4; nt++) {
        float bb = bias[(nt << 4) + ml];
#pragma unroll
        for (int i = 0; i < 4; i++) {
            int node = node0 + w16 + (kg << 2) + i;
            out[(size_t)node * F + (nt << 4) + ml] = acc[nt][i] + bb;
        }
    }
}

extern "C" void kernel_launch(void* const* d_in, const int* in_sizes, int n_in,
                              void* d_out, int out_size, void* d_ws, size_t ws_size,
                              hipStream_t stream) {
    const float* x    = (const float*)d_in[0];
    const int*   ei   = (const int*)d_in[1];
    const int*   et   = (const int*)d_in[2];
    const float* wgt  = (const float*)d_in[3];
    const float* root = (const float*)d_in[4];
    const float* bias = (const float*)d_in[5];
    float*       out  = (float*)d_out;

    int*      cursors = (int*)d_ws;                                   // [128]
    unsigned* runsd   = (unsigned*)((char*)d_ws + 512);               // [784*32]
    unsigned* stag4   = (unsigned*)((char*)d_ws + 512 + 100352);      // 14.5 MB
    unsigned* packed4 = stag4 + (size_t)NCB * CAPC;                   // 14.5 MB
    __half*   xh      = (__half*)(packed4 + (size_t)NCB * CAPC);      // 12.8 MB
    __half*   wt9     = xh + (size_t)NN * F;                          // 72 KB

    init_kernel<<<1, 128, 0, stream>>>(cursors);
    cvt_kernel<<<NN * F / (256 * 8), 256, 0, stream>>>(x, xh);
    cvtw_kernel<<<144, 256, 0, stream>>>(wgt, root, wt9);
    binA_kernel<<<NE / CHUNKA, 256, 0, stream>>>(ei, ei + NE, et, cursors, stag4);
    binB_kernel<<<NCB * 8, 256, 0, stream>>>(stag4, cursors, packed4, runsd);
    fused_kernel<<<NT, 128, 0, stream>>>(xh, packed4, runsd, wt9, bias, out);
}